// Round 6
// baseline (2707.916 us; speedup 1.0000x reference)
//
#include <hip/hip_runtime.h>

using i16x8 = __attribute__((ext_vector_type(8))) short;
using bfx8  = __attribute__((ext_vector_type(8))) __bf16;
using fx4   = __attribute__((ext_vector_type(4))) float;

__device__ inline unsigned short f2bf(float f) {
  unsigned int u = __float_as_uint(f);
  u += 0x7fffu + ((u >> 16) & 1u);
  return (unsigned short)(u >> 16);
}
__device__ inline float bf2f(unsigned short s) {
  return __uint_as_float(((unsigned int)s) << 16);
}

__device__ inline fx4 mfma_bf16(i16x8 a, i16x8 b, fx4 c) {
  return __builtin_amdgcn_mfma_f32_16x16x32_bf16(
      __builtin_bit_cast(bfx8, a), __builtin_bit_cast(bfx8, b), c, 0, 0, 0);
}

__device__ inline void gld_lds16(const unsigned short* g, unsigned short* l) {
  __builtin_amdgcn_global_load_lds(
      (const __attribute__((address_space(1))) unsigned int*)g,
      (__attribute__((address_space(3))) unsigned int*)l, 16, 0, 0);
}

__device__ inline float block_sum256(float v, float* red, int tid) {
  #pragma unroll
  for (int off = 32; off > 0; off >>= 1) v += __shfl_down(v, off);
  __syncthreads();
  if ((tid & 63) == 0) red[tid >> 6] = v;
  __syncthreads();
  return red[0] + red[1] + red[2] + red[3];
}

__global__ void k_zero(unsigned* p) {
  if (threadIdx.x == 0) *p = 0u;
}

// ---------------- fp32 -> bf16 conversion with optional zero column pad ----
__global__ __launch_bounds__(256) void k_conv(const float* __restrict__ src,
                                              unsigned short* __restrict__ dst,
                                              int R, int C, int Cp) {
  long long total = (long long)R * Cp;
  long long stride = (long long)gridDim.x * 256;
  if (C == Cp) {
    for (long long i = blockIdx.x * 256LL + threadIdx.x; i < total; i += stride)
      dst[i] = f2bf(src[i]);
  } else {
    for (long long i = blockIdx.x * 256LL + threadIdx.x; i < total; i += stride) {
      int r = (int)(i / Cp), c = (int)(i % Cp);
      dst[i] = (c < C) ? f2bf(src[(long long)r * C + c]) : (unsigned short)0;
    }
  }
}

// ---------------- h0 = tanh(noise @ W_init^T + b_init) ----------------------
__global__ __launch_bounds__(512) void k_h0(const float* __restrict__ noise,
                                            const float* __restrict__ Wi,
                                            const float* __restrict__ bi,
                                            float* __restrict__ h0f,
                                            unsigned short* __restrict__ hb) {
  int b = blockIdx.x, j = threadIdx.x;
  const float* nr = noise + b * 100;
  const float* wr = Wi + j * 100;
  float s = bi[j];
  for (int k = 0; k < 100; ++k) s += nr[k] * wr[k];
  float h = tanhf(s);
  h0f[b * 512 + j] = h;
  hb[b * 512 + j] = f2bf(h);
}

// ---------------- bf16 MFMA GEMM: C[m][n] = sum_k A[m][k] * W[n][k] + bias --
// 128x128 tile, BK=32, 4 waves (2x2), global_load_lds staging (m97 structure)
template <int OUTBF>
__global__ __launch_bounds__(256, 2) void k_gemm(
    const unsigned short* __restrict__ A, int lda,
    const unsigned short* __restrict__ W, int ldw, int nw,
    float* __restrict__ Cf, unsigned short* __restrict__ Cb, int ldc,
    const float* __restrict__ bias, int Nreal, int K) {
  __shared__ unsigned short As[128 * 32];
  __shared__ unsigned short Bs[128 * 32];
  const int tid = threadIdx.x;
  const int lane = tid & 63;
  const int w = tid >> 6;
  const int wm = w >> 1, wn = w & 1;
  const int c = lane & 15, kg = lane >> 4;
  const int m0 = blockIdx.y * 128;
  const int n0 = blockIdx.x * 128;

  fx4 acc[4][4];
  #pragma unroll
  for (int i = 0; i < 4; ++i)
    #pragma unroll
    for (int j = 0; j < 4; ++j) acc[i][j] = (fx4){0.f, 0.f, 0.f, 0.f};

  for (int kt = 0; kt < K; kt += 32) {
    __syncthreads();  // protect LDS from previous iteration's readers
    #pragma unroll
    for (int it = 0; it < 2; ++it) {
      int ch = it * 256 + tid;
      int row = ch >> 2, seg = ch & 3;
      const unsigned short* ga = A + (size_t)(m0 + row) * lda + kt + seg * 8;
      int wr = n0 + row;
      if (wr >= nw) wr = nw - 1;  // clamp: finite values, cols store-guarded
      const unsigned short* gb = W + (size_t)wr * ldw + kt + seg * 8;
      gld_lds16(ga, &As[(it * 256 + w * 64) * 8]);
      gld_lds16(gb, &Bs[(it * 256 + w * 64) * 8]);
    }
    __syncthreads();
    i16x8 af[4], bf[4];
    #pragma unroll
    for (int i = 0; i < 4; ++i)
      af[i] = *(const i16x8*)&As[(wm * 64 + i * 16 + c) * 32 + kg * 8];
    #pragma unroll
    for (int j = 0; j < 4; ++j)
      bf[j] = *(const i16x8*)&Bs[(wn * 64 + j * 16 + c) * 32 + kg * 8];
    #pragma unroll
    for (int i = 0; i < 4; ++i)
      #pragma unroll
      for (int j = 0; j < 4; ++j)
        acc[i][j] = mfma_bf16(af[i], bf[j], acc[i][j]);
  }

  #pragma unroll
  for (int j = 0; j < 4; ++j) {
    int n = n0 + wn * 64 + j * 16 + c;
    if (n >= Nreal) continue;
    float bv = bias ? bias[n] : 0.f;
    #pragma unroll
    for (int i = 0; i < 4; ++i) {
      #pragma unroll
      for (int r = 0; r < 4; ++r) {
        int m = m0 + wm * 64 + i * 16 + kg * 4 + r;
        float v = acc[i][j][r] + bv;
        if (OUTBF) Cb[(size_t)m * ldc + n] = f2bf(v);
        else       Cf[(size_t)m * ldc + n] = v;
      }
    }
  }
}

// ---------------- rowwise LayerNorm + relu -> bf16 (zero pad to Np) ---------
__global__ __launch_bounds__(256) void k_ln(const float* __restrict__ y, int ldy, int N,
                                            unsigned short* __restrict__ out, int ldo, int Np,
                                            const float* __restrict__ g,
                                            const float* __restrict__ b) {
  __shared__ float red[4];
  int m = blockIdx.x, tid = threadIdx.x;
  const float* row = y + (size_t)m * ldy;
  float s = 0.f, s2 = 0.f;
  for (int c = tid; c < N; c += 256) { float v = row[c]; s += v; s2 += v * v; }
  float S = block_sum256(s, red, tid);
  float S2 = block_sum256(s2, red, tid);
  float mean = S / N;
  float var = S2 / N - mean * mean;
  float rstd = rsqrtf(var + 1e-5f);
  unsigned short* orow = out + (size_t)m * ldo;
  for (int c = tid; c < N; c += 256) {
    float v = (row[c] - mean) * rstd * g[c] + b[c];
    orow[c] = f2bf(v > 0.f ? v : 0.f);
  }
  for (int c = N + tid; c < Np; c += 256) orow[c] = 0;
}

// ---------------- GRU scan: persistent, 32 blocks x 256 thr -----------------
// Fence-free handshake: h exchanged via AGENT-scope relaxed atomics (coherent,
// bypasses per-XCD L2), monotonic counter barrier, gi(t+1) prefetched under
// the spin. No __threadfence -> local L2 stays warm for gi/hseq traffic.
__global__ __launch_bounds__(256, 1) void k_scan(
    const unsigned short* __restrict__ gi,    // [B*T][1536], m = b*256+t
    const unsigned short* __restrict__ Whh,   // [1536][512] bf16
    const float* __restrict__ bhh,            // [1536]
    const float* __restrict__ h0f,            // [64][512] f32
    unsigned short* __restrict__ hA,          // [64][512] bf16 (t even src)
    unsigned short* __restrict__ hB,          // [64][512] bf16
    unsigned short* __restrict__ hseq,        // [B*T][512] bf16
    unsigned* __restrict__ ctr) {             // spin-barrier counter (zeroed)
  const int tid = threadIdx.x;
  const int lane = tid & 63;
  const int w = tid >> 6;
  const int c = lane & 15, kg = lane >> 4;
  const int jb = blockIdx.x * 16;
  const int j = jb + c;
  const int b0 = w * 16;

  // B-operand fragments for the 3 gate rows of column j, all K=512: 48x16B
  i16x8 bfr[16], bfz[16], bfn[16];
  #pragma unroll
  for (int ks = 0; ks < 16; ++ks) {
    bfr[ks] = *(const i16x8*)(Whh + (size_t)(j)        * 512 + ks * 32 + kg * 8);
    bfz[ks] = *(const i16x8*)(Whh + (size_t)(512 + j)  * 512 + ks * 32 + kg * 8);
    bfn[ks] = *(const i16x8*)(Whh + (size_t)(1024 + j) * 512 + ks * 32 + kg * 8);
  }
  const float br = bhh[j], bz = bhh[512 + j], bn = bhh[1024 + j];

  float hl[4];
  #pragma unroll
  for (int r = 0; r < 4; ++r) hl[r] = h0f[(b0 + kg * 4 + r) * 512 + j];

  unsigned short* hc = hA;
  unsigned short* hn = hB;

  // gi registers for current step (prefetched)
  float ir[4], iz[4], inn[4];
  #pragma unroll
  for (int r = 0; r < 4; ++r) {
    size_t base = ((size_t)(b0 + kg * 4 + r) * 256 + 0) * 1536 + j;
    ir[r]  = bf2f(gi[base]);
    iz[r]  = bf2f(gi[base + 512]);
    inn[r] = bf2f(gi[base + 1024]);
  }

  #pragma unroll 1
  for (int t = 0; t < 256; ++t) {
    // gh = h(t) @ Whh^T for owned columns: coherent dword loads of h frags
    const unsigned int* hc32 = (const unsigned int*)hc;
    fx4 ar = {0.f, 0.f, 0.f, 0.f}, az = ar, an = ar;
    #pragma unroll
    for (int ks = 0; ks < 16; ++ks) {
      union { unsigned int d[4]; i16x8 v; } u;
      size_t dbase = (size_t)(b0 + c) * 256 + ks * 16 + kg * 4;
      #pragma unroll
      for (int d = 0; d < 4; ++d)
        u.d[d] = __hip_atomic_load(hc32 + dbase + d,
                                   __ATOMIC_RELAXED, __HIP_MEMORY_SCOPE_AGENT);
      ar = mfma_bf16(u.v, bfr[ks], ar);
      az = mfma_bf16(u.v, bfz[ks], az);
      an = mfma_bf16(u.v, bfn[ks], an);
    }

    #pragma unroll
    for (int r = 0; r < 4; ++r) {
      int b = b0 + kg * 4 + r;
      float rg = 1.f / (1.f + __expf(-(ir[r] + ar[r] + br)));
      float zg = 1.f / (1.f + __expf(-(iz[r] + az[r] + bz)));
      float ng = tanhf(inn[r] + rg * (an[r] + bn));
      float h = (1.f - zg) * ng + zg * hl[r];
      hl[r] = h;
      unsigned short hv = f2bf(h);
      // coherent (agent-visible) store for the next step's cross-XCD readers
      __hip_atomic_store(hn + (size_t)b * 512 + j, hv,
                         __ATOMIC_RELAXED, __HIP_MEMORY_SCOPE_AGENT);
      hseq[((size_t)b * 256 + t) * 512 + j] = hv;  // plain cached store
    }

    if (t < 255) {
      // __syncthreads drains each thread's vmcnt before s_barrier -> all
      // coherent h-stores are acked at the device coherence point.
      __syncthreads();
      unsigned target = 32u * (unsigned)(t + 1);
      if (tid == 0)
        __hip_atomic_fetch_add(ctr, 1u, __ATOMIC_RELAXED, __HIP_MEMORY_SCOPE_AGENT);
      // prefetch gi(t+1) while tid0 spins (plain cached loads, L2 stays warm)
      float ir2[4], iz2[4], inn2[4];
      #pragma unroll
      for (int r = 0; r < 4; ++r) {
        size_t base = ((size_t)(b0 + kg * 4 + r) * 256 + (t + 1)) * 1536 + j;
        ir2[r]  = bf2f(gi[base]);
        iz2[r]  = bf2f(gi[base + 512]);
        inn2[r] = bf2f(gi[base + 1024]);
      }
      if (tid == 0) {
        while (__hip_atomic_load(ctr, __ATOMIC_RELAXED, __HIP_MEMORY_SCOPE_AGENT) < target)
          __builtin_amdgcn_s_sleep(1);
      }
      __syncthreads();
      #pragma unroll
      for (int r = 0; r < 4; ++r) { ir[r] = ir2[r]; iz[r] = iz2[r]; inn[r] = inn2[r]; }
      unsigned short* tmp = hc; hc = hn; hn = tmp;
    }
  }
}

// ---------------- fused diag-Gaussian logprob per (b,t) row -----------------
__global__ __launch_bounds__(256) void k_logprob(const float* __restrict__ x,
                                                 const unsigned short* __restrict__ mu,
                                                 const unsigned short* __restrict__ ls,
                                                 float* __restrict__ lp) {
  __shared__ float red[4];
  int m = blockIdx.x, tid = threadIdx.x;
  const float* xr = x + (size_t)m * 768;
  const unsigned short* mr = mu + (size_t)m * 768;
  const unsigned short* lr = ls + (size_t)m * 768;
  float a1 = 0.f, a2 = 0.f;
  for (int c = tid; c < 768; c += 256) {
    float xv = xr[c], mv = bf2f(mr[c]), lv = bf2f(lr[c]);
    float d = xv - mv;
    a1 += d * d * expf(-lv);
    a2 += lv;
  }
  float A1 = block_sum256(a1, red, tid);
  float A2 = block_sum256(a2, red, tid);
  if (tid == 0)
    lp[m] = -0.5f * (A1 + A2 + 768.0f * 1.8378770664093453f);
}

// ---------------- masked mean over t --------------------------------------
__global__ __launch_bounds__(256) void k_final(const float* __restrict__ lp,
                                               const int* __restrict__ len,
                                               float* __restrict__ out) {
  __shared__ float red[4];
  int b = blockIdx.x, tid = threadIdx.x;
  int L = len[b];
  float v = (tid >= 1 && tid < L) ? lp[b * 256 + tid] : 0.f;
  float S = block_sum256(v, red, tid);
  if (tid == 0) out[b] = S / (float)L;
}

extern "C" void kernel_launch(void* const* d_in, const int* in_sizes, int n_in,
                              void* d_out, int out_size, void* d_ws, size_t ws_size,
                              hipStream_t stream) {
  const float* x        = (const float*)d_in[0];
  const int*   lengths  = (const int*)d_in[1];
  const float* h0_noise = (const float*)d_in[3];
  const float* W_lin_in = (const float*)d_in[4];
  const float* b_lin_in = (const float*)d_in[5];
  const float* g_ln1    = (const float*)d_in[6];
  const float* b_ln1    = (const float*)d_in[7];
  const float* W_ih     = (const float*)d_in[8];
  const float* W_hh     = (const float*)d_in[9];
  const float* b_ih     = (const float*)d_in[10];
  const float* b_hh     = (const float*)d_in[11];
  const float* W_init   = (const float*)d_in[12];
  const float* b_init   = (const float*)d_in[13];
  const float* W_lin1   = (const float*)d_in[14];
  const float* b_lin1   = (const float*)d_in[15];
  const float* g_ln2    = (const float*)d_in[16];
  const float* b_ln2    = (const float*)d_in[17];
  const float* W_mu     = (const float*)d_in[18];
  const float* b_mu     = (const float*)d_in[19];
  const float* W_sig    = (const float*)d_in[20];
  const float* b_sig    = (const float*)d_in[21];

  char* ws = (char*)d_ws;
  size_t off = 0;
  auto alloc = [&](size_t bytes) -> void* {
    void* p = ws + off;
    off += (bytes + 255) & ~(size_t)255;
    return p;
  };
  unsigned short* xbf      = (unsigned short*)alloc(16384ull * 768 * 2);
  unsigned short* Wlin_bf  = (unsigned short*)alloc(400ull * 768 * 2);
  unsigned short* Wih_bf   = (unsigned short*)alloc(1536ull * 448 * 2);
  unsigned short* Whh_bf   = (unsigned short*)alloc(1536ull * 512 * 2);
  unsigned short* Wlin1_bf = (unsigned short*)alloc(768ull * 512 * 2);
  unsigned short* Wmu_bf   = (unsigned short*)alloc(768ull * 768 * 2);
  unsigned short* Wsig_bf  = (unsigned short*)alloc(768ull * 768 * 2);
  float*          y        = (float*)alloc(16384ull * 768 * 4);   // y1 (ld448) then y2 (ld768)
  unsigned short* r_bf     = (unsigned short*)alloc(16384ull * 448 * 2);
  unsigned short* gi_bf    = (unsigned short*)alloc(16384ull * 1536 * 2);
  float*          h0f      = (float*)alloc(64ull * 512 * 4);
  unsigned short* hbf0     = (unsigned short*)alloc(64ull * 512 * 2);
  unsigned short* hbf1     = (unsigned short*)alloc(64ull * 512 * 2);
  unsigned short* hseq     = (unsigned short*)alloc(16384ull * 512 * 2);
  unsigned short* hh_bf    = (unsigned short*)alloc(16384ull * 768 * 2);
  unsigned short* mu_bf    = (unsigned short*)alloc(16384ull * 768 * 2);
  unsigned short* ls_bf    = (unsigned short*)alloc(16384ull * 768 * 2);
  float*          lp       = (float*)alloc(16384ull * 4);
  unsigned*       bar      = (unsigned*)alloc(256);
  if (off > ws_size) return;  // workspace too small: leave output zeroed as a clear signal

  auto cgrid = [](long long n) { long long b = (n + 255) / 256; return (int)(b > 4096 ? 4096 : b); };

  // fp32 -> bf16 conversions (+ zero K-pad for W_ih)
  k_conv<<<dim3(cgrid(16384ll * 768)), 256, 0, stream>>>(x, xbf, 16384, 768, 768);
  k_conv<<<dim3(cgrid(400ll * 768)),   256, 0, stream>>>(W_lin_in, Wlin_bf, 400, 768, 768);
  k_conv<<<dim3(cgrid(1536ll * 448)),  256, 0, stream>>>(W_ih, Wih_bf, 1536, 400, 448);
  k_conv<<<dim3(cgrid(1536ll * 512)),  256, 0, stream>>>(W_hh, Whh_bf, 1536, 512, 512);
  k_conv<<<dim3(cgrid(768ll * 512)),   256, 0, stream>>>(W_lin1, Wlin1_bf, 768, 512, 512);
  k_conv<<<dim3(cgrid(768ll * 768)),   256, 0, stream>>>(W_mu, Wmu_bf, 768, 768, 768);
  k_conv<<<dim3(cgrid(768ll * 768)),   256, 0, stream>>>(W_sig, Wsig_bf, 768, 768, 768);

  // h0 (f32 + bf16)
  k_h0<<<dim3(64), 512, 0, stream>>>(h0_noise, W_init, b_init, h0f, hbf0);

  // y1 = x @ W_lin_in^T + b  (f32 out, ld 448, N=400)
  k_gemm<0><<<dim3(4, 128), 256, 0, stream>>>(xbf, 768, Wlin_bf, 768, 400,
                                              y, nullptr, 448, b_lin_in, 400, 768);
  // r = relu(LN(y1)) -> bf16 [16384][448], zero pad cols 400..447
  k_ln<<<dim3(16384), 256, 0, stream>>>(y, 448, 400, r_bf, 448, 448, g_ln1, b_ln1);
  // gi = r @ W_ih^T + b_ih (bf16 out)
  k_gemm<1><<<dim3(12, 128), 256, 0, stream>>>(r_bf, 448, Wih_bf, 448, 1536,
                                               nullptr, gi_bf, 1536, b_ih, 1536, 448);

  // GRU scan: persistent 32-block kernel, fence-free coherent handshake
  k_zero<<<dim3(1), 64, 0, stream>>>(bar);
  k_scan<<<dim3(32), 256, 0, stream>>>(gi_bf, Whh_bf, b_hh, h0f, hbf0, hbf1, hseq, bar);

  // y2 = hseq @ W_lin1^T + b (f32 out, ld 768)
  k_gemm<0><<<dim3(6, 128), 256, 0, stream>>>(hseq, 512, Wlin1_bf, 512, 768,
                                              y, nullptr, 768, b_lin1, 768, 512);
  // hh = relu(LN(y2)) -> bf16 [16384][768]
  k_ln<<<dim3(16384), 256, 0, stream>>>(y, 768, 768, hh_bf, 768, 768, g_ln2, b_ln2);
  // mu, logsig (bf16 out)
  k_gemm<1><<<dim3(6, 128), 256, 0, stream>>>(hh_bf, 768, Wmu_bf, 768, 768,
                                              nullptr, mu_bf, 768, b_mu, 768, 768);
  k_gemm<1><<<dim3(6, 128), 256, 0, stream>>>(hh_bf, 768, Wsig_bf, 768, 768,
                                              nullptr, ls_bf, 768, b_sig, 768, 768);

  // lp[b*256+t], then masked mean over t
  k_logprob<<<dim3(16384), 256, 0, stream>>>(x, mu_bf, ls_bf, lp);
  k_final<<<dim3(64), 256, 0, stream>>>(lp, lengths, (float*)d_out);
}

// Round 7
// 2186.430 us; speedup vs baseline: 1.2385x; 1.2385x over previous
//
#include <hip/hip_runtime.h>

using i16x8 = __attribute__((ext_vector_type(8))) short;
using bfx8  = __attribute__((ext_vector_type(8))) __bf16;
using fx4   = __attribute__((ext_vector_type(4))) float;

__device__ inline unsigned short f2bf(float f) {
  unsigned int u = __float_as_uint(f);
  u += 0x7fffu + ((u >> 16) & 1u);
  return (unsigned short)(u >> 16);
}
__device__ inline float bf2f(unsigned short s) {
  return __uint_as_float(((unsigned int)s) << 16);
}

__device__ inline fx4 mfma_bf16(i16x8 a, i16x8 b, fx4 c) {
  return __builtin_amdgcn_mfma_f32_16x16x32_bf16(
      __builtin_bit_cast(bfx8, a), __builtin_bit_cast(bfx8, b), c, 0, 0, 0);
}

__device__ inline void gld_lds16(const unsigned short* g, unsigned short* l) {
  __builtin_amdgcn_global_load_lds(
      (const __attribute__((address_space(1))) unsigned int*)g,
      (__attribute__((address_space(3))) unsigned int*)l, 16, 0, 0);
}

__device__ inline float block_sum256(float v, float* red, int tid) {
  #pragma unroll
  for (int off = 32; off > 0; off >>= 1) v += __shfl_down(v, off);
  __syncthreads();
  if ((tid & 63) == 0) red[tid >> 6] = v;
  __syncthreads();
  return red[0] + red[1] + red[2] + red[3];
}

// coherent (cross-XCD) 16-B load: bypass L1/L2, read at device coherence point
__device__ inline fx4 cload16(const void* p) {
  fx4 r;
  asm volatile("global_load_dwordx4 %0, %1, off sc0 sc1"
               : "=v"(r)
               : "v"((unsigned long long)(uintptr_t)p)
               : "memory");
  return r;
}
// coherent 2-B store (write-through to coherence point)
__device__ inline void cstore16b(void* p, unsigned short v) {
  asm volatile("global_store_short %0, %1, off sc0 sc1"
               :: "v"((unsigned long long)(uintptr_t)p), "v"((unsigned)v)
               : "memory");
}
__device__ inline void cstore32b(void* p, unsigned v) {
  asm volatile("global_store_dword %0, %1, off sc0 sc1"
               :: "v"((unsigned long long)(uintptr_t)p), "v"(v)
               : "memory");
}

__global__ void k_zero(unsigned* p) {
  p[threadIdx.x] = 0u;  // 256 dwords
}

// ---------------- fp32 -> bf16 conversion with optional zero column pad ----
__global__ __launch_bounds__(256) void k_conv(const float* __restrict__ src,
                                              unsigned short* __restrict__ dst,
                                              int R, int C, int Cp) {
  long long total = (long long)R * Cp;
  long long stride = (long long)gridDim.x * 256;
  if (C == Cp) {
    for (long long i = blockIdx.x * 256LL + threadIdx.x; i < total; i += stride)
      dst[i] = f2bf(src[i]);
  } else {
    for (long long i = blockIdx.x * 256LL + threadIdx.x; i < total; i += stride) {
      int r = (int)(i / Cp), c = (int)(i % Cp);
      dst[i] = (c < C) ? f2bf(src[(long long)r * C + c]) : (unsigned short)0;
    }
  }
}

// ---------------- h0 = tanh(noise @ W_init^T + b_init) ----------------------
__global__ __launch_bounds__(512) void k_h0(const float* __restrict__ noise,
                                            const float* __restrict__ Wi,
                                            const float* __restrict__ bi,
                                            float* __restrict__ h0f,
                                            unsigned short* __restrict__ hb) {
  int b = blockIdx.x, j = threadIdx.x;
  const float* nr = noise + b * 100;
  const float* wr = Wi + j * 100;
  float s = bi[j];
  for (int k = 0; k < 100; ++k) s += nr[k] * wr[k];
  float h = tanhf(s);
  h0f[b * 512 + j] = h;
  hb[b * 512 + j] = f2bf(h);
}

// ---------------- bf16 MFMA GEMM: C[m][n] = sum_k A[m][k] * W[n][k] + bias --
// 128x128 tile, BK=32, 4 waves (2x2), global_load_lds staging (m97 structure)
template <int OUTBF>
__global__ __launch_bounds__(256, 2) void k_gemm(
    const unsigned short* __restrict__ A, int lda,
    const unsigned short* __restrict__ W, int ldw, int nw,
    float* __restrict__ Cf, unsigned short* __restrict__ Cb, int ldc,
    const float* __restrict__ bias, int Nreal, int K) {
  __shared__ unsigned short As[128 * 32];
  __shared__ unsigned short Bs[128 * 32];
  const int tid = threadIdx.x;
  const int lane = tid & 63;
  const int w = tid >> 6;
  const int wm = w >> 1, wn = w & 1;
  const int c = lane & 15, kg = lane >> 4;
  const int m0 = blockIdx.y * 128;
  const int n0 = blockIdx.x * 128;

  fx4 acc[4][4];
  #pragma unroll
  for (int i = 0; i < 4; ++i)
    #pragma unroll
    for (int j = 0; j < 4; ++j) acc[i][j] = (fx4){0.f, 0.f, 0.f, 0.f};

  for (int kt = 0; kt < K; kt += 32) {
    __syncthreads();  // protect LDS from previous iteration's readers
    #pragma unroll
    for (int it = 0; it < 2; ++it) {
      int ch = it * 256 + tid;
      int row = ch >> 2, seg = ch & 3;
      const unsigned short* ga = A + (size_t)(m0 + row) * lda + kt + seg * 8;
      int wr = n0 + row;
      if (wr >= nw) wr = nw - 1;  // clamp: finite values, cols store-guarded
      const unsigned short* gb = W + (size_t)wr * ldw + kt + seg * 8;
      gld_lds16(ga, &As[(it * 256 + w * 64) * 8]);
      gld_lds16(gb, &Bs[(it * 256 + w * 64) * 8]);
    }
    __syncthreads();
    i16x8 af[4], bf[4];
    #pragma unroll
    for (int i = 0; i < 4; ++i)
      af[i] = *(const i16x8*)&As[(wm * 64 + i * 16 + c) * 32 + kg * 8];
    #pragma unroll
    for (int j = 0; j < 4; ++j)
      bf[j] = *(const i16x8*)&Bs[(wn * 64 + j * 16 + c) * 32 + kg * 8];
    #pragma unroll
    for (int i = 0; i < 4; ++i)
      #pragma unroll
      for (int j = 0; j < 4; ++j)
        acc[i][j] = mfma_bf16(af[i], bf[j], acc[i][j]);
  }

  #pragma unroll
  for (int j = 0; j < 4; ++j) {
    int n = n0 + wn * 64 + j * 16 + c;
    if (n >= Nreal) continue;
    float bv = bias ? bias[n] : 0.f;
    #pragma unroll
    for (int i = 0; i < 4; ++i) {
      #pragma unroll
      for (int r = 0; r < 4; ++r) {
        int m = m0 + wm * 64 + i * 16 + kg * 4 + r;
        float v = acc[i][j][r] + bv;
        if (OUTBF) Cb[(size_t)m * ldc + n] = f2bf(v);
        else       Cf[(size_t)m * ldc + n] = v;
      }
    }
  }
}

// ---------------- rowwise LayerNorm + relu -> bf16 (zero pad to Np) ---------
__global__ __launch_bounds__(256) void k_ln(const float* __restrict__ y, int ldy, int N,
                                            unsigned short* __restrict__ out, int ldo, int Np,
                                            const float* __restrict__ g,
                                            const float* __restrict__ b) {
  __shared__ float red[4];
  int m = blockIdx.x, tid = threadIdx.x;
  const float* row = y + (size_t)m * ldy;
  float s = 0.f, s2 = 0.f;
  for (int c = tid; c < N; c += 256) { float v = row[c]; s += v; s2 += v * v; }
  float S = block_sum256(s, red, tid);
  float S2 = block_sum256(s2, red, tid);
  float mean = S / N;
  float var = S2 / N - mean * mean;
  float rstd = rsqrtf(var + 1e-5f);
  unsigned short* orow = out + (size_t)m * ldo;
  for (int c = tid; c < N; c += 256) {
    float v = (row[c] - mean) * rstd * g[c] + b[c];
    orow[c] = f2bf(v > 0.f ? v : 0.f);
  }
  for (int c = N + tid; c < Np; c += 256) orow[c] = 0;
}

// ---------------- GRU scan: persistent, 32 blocks x 256 thr -----------------
// Wave-granular mailbox barrier: 128 flags (one per wave, packed dwords).
// Each wave: coherent-store its h chunk -> vmcnt(0) -> raise own flag ->
// prefetch gi(t+1) -> wave-parallel poll of all 128 flags. No __syncthreads,
// no LDS, no shared counter RMW contention.
__global__ __launch_bounds__(256, 1) void k_scan(
    const unsigned short* __restrict__ gi,    // [B*T][1536], m = b*256+t
    const unsigned short* __restrict__ Whh,   // [1536][512] bf16
    const float* __restrict__ bhh,            // [1536]
    const float* __restrict__ h0f,            // [64][512] f32
    unsigned short* __restrict__ hA,          // [64][512] bf16 (= h0 bf16)
    unsigned short* __restrict__ hB,          // [64][512] bf16
    unsigned short* __restrict__ hseq,        // [B*T][512] bf16
    unsigned* __restrict__ flags) {           // 128+ dwords, zeroed
  const int tid = threadIdx.x;
  const int lane = tid & 63;
  const int w = tid >> 6;
  const int c = lane & 15, kg = lane >> 4;
  const int bid = blockIdx.x;
  const int j = bid * 16 + c;
  const int b0 = w * 16;

  // B-operand fragments for the 3 gate rows of column j, all K=512: 48x16B
  i16x8 bfr[16], bfz[16], bfn[16];
  #pragma unroll
  for (int ks = 0; ks < 16; ++ks) {
    bfr[ks] = *(const i16x8*)(Whh + (size_t)(j)        * 512 + ks * 32 + kg * 8);
    bfz[ks] = *(const i16x8*)(Whh + (size_t)(512 + j)  * 512 + ks * 32 + kg * 8);
    bfn[ks] = *(const i16x8*)(Whh + (size_t)(1024 + j) * 512 + ks * 32 + kg * 8);
  }
  const float br = bhh[j], bz = bhh[512 + j], bn = bhh[1024 + j];

  float hl[4];
  #pragma unroll
  for (int r = 0; r < 4; ++r) hl[r] = h0f[(b0 + kg * 4 + r) * 512 + j];

  const unsigned short* hc = hA;
  unsigned short* hn = hB;

  // gi registers for current step (prefetched)
  float ir[4], iz[4], inn[4];
  #pragma unroll
  for (int r = 0; r < 4; ++r) {
    size_t base = ((size_t)(b0 + kg * 4 + r) * 256 + 0) * 1536 + j;
    ir[r]  = bf2f(gi[base]);
    iz[r]  = bf2f(gi[base + 512]);
    inn[r] = bf2f(gi[base + 1024]);
  }

  #pragma unroll 1
  for (int t = 0; t < 256; ++t) {
    // issue coherent wide loads of h(t) fragments, then drain
    fx4 hf[16];
    #pragma unroll
    for (int ks = 0; ks < 16; ++ks)
      hf[ks] = cload16(hc + (size_t)(b0 + c) * 512 + ks * 32 + kg * 8);
    asm volatile("s_waitcnt vmcnt(0)" ::: "memory");
    __builtin_amdgcn_sched_barrier(0);

    fx4 ar = {0.f, 0.f, 0.f, 0.f}, az = ar, an = ar;
    #pragma unroll
    for (int ks = 0; ks < 16; ++ks) {
      i16x8 a = __builtin_bit_cast(i16x8, hf[ks]);
      ar = mfma_bf16(a, bfr[ks], ar);
      az = mfma_bf16(a, bfz[ks], az);
      an = mfma_bf16(a, bfn[ks], an);
    }

    #pragma unroll
    for (int r = 0; r < 4; ++r) {
      int b = b0 + kg * 4 + r;
      float rg = 1.f / (1.f + __expf(-(ir[r] + ar[r] + br)));
      float zg = 1.f / (1.f + __expf(-(iz[r] + az[r] + bz)));
      float ng = tanhf(inn[r] + rg * (an[r] + bn));
      float h = (1.f - zg) * ng + zg * hl[r];
      hl[r] = h;
      unsigned short hv = f2bf(h);
      cstore16b(hn + (size_t)b * 512 + j, hv);        // coherent, cross-XCD
      hseq[((size_t)b * 256 + t) * 512 + j] = hv;     // plain cached store
    }

    if (t < 255) {
      // ack all h stores at the coherence point, then raise this wave's flag
      asm volatile("s_waitcnt vmcnt(0)" ::: "memory");
      if (lane == 0)
        cstore32b(&flags[bid * 4 + w], (unsigned)(t + 1));

      // prefetch gi(t+1) with plain cached loads; completes under the poll
      float ir2[4], iz2[4], inn2[4];
      #pragma unroll
      for (int r = 0; r < 4; ++r) {
        size_t base = ((size_t)(b0 + kg * 4 + r) * 256 + (t + 1)) * 1536 + j;
        ir2[r]  = bf2f(gi[base]);
        iz2[r]  = bf2f(gi[base + 512]);
        inn2[r] = bf2f(gi[base + 1024]);
      }

      // wave-parallel poll: lane l watches flags[l] and flags[64+l]
      unsigned tgt = (unsigned)(t + 1);
      int guard = 0;
      bool ok;
      do {
        unsigned f0 = __hip_atomic_load(flags + lane, __ATOMIC_RELAXED,
                                        __HIP_MEMORY_SCOPE_AGENT);
        unsigned f1 = __hip_atomic_load(flags + 64 + lane, __ATOMIC_RELAXED,
                                        __HIP_MEMORY_SCOPE_AGENT);
        ok = __all((f0 >= tgt) && (f1 >= tgt));
        if (!ok) __builtin_amdgcn_s_sleep(1);
      } while (!ok && ++guard < 1000000);

      #pragma unroll
      for (int r = 0; r < 4; ++r) { ir[r] = ir2[r]; iz[r] = iz2[r]; inn[r] = inn2[r]; }
      const unsigned short* tmp = hc; hc = hn; hn = (unsigned short*)tmp;
    }
  }
}

// ---------------- fused diag-Gaussian logprob per (b,t) row -----------------
__global__ __launch_bounds__(256) void k_logprob(const float* __restrict__ x,
                                                 const unsigned short* __restrict__ mu,
                                                 const unsigned short* __restrict__ ls,
                                                 float* __restrict__ lp) {
  __shared__ float red[4];
  int m = blockIdx.x, tid = threadIdx.x;
  const float* xr = x + (size_t)m * 768;
  const unsigned short* mr = mu + (size_t)m * 768;
  const unsigned short* lr = ls + (size_t)m * 768;
  float a1 = 0.f, a2 = 0.f;
  for (int c = tid; c < 768; c += 256) {
    float xv = xr[c], mv = bf2f(mr[c]), lv = bf2f(lr[c]);
    float d = xv - mv;
    a1 += d * d * expf(-lv);
    a2 += lv;
  }
  float A1 = block_sum256(a1, red, tid);
  float A2 = block_sum256(a2, red, tid);
  if (tid == 0)
    lp[m] = -0.5f * (A1 + A2 + 768.0f * 1.8378770664093453f);
}

// ---------------- masked mean over t --------------------------------------
__global__ __launch_bounds__(256) void k_final(const float* __restrict__ lp,
                                               const int* __restrict__ len,
                                               float* __restrict__ out) {
  __shared__ float red[4];
  int b = blockIdx.x, tid = threadIdx.x;
  int L = len[b];
  float v = (tid >= 1 && tid < L) ? lp[b * 256 + tid] : 0.f;
  float S = block_sum256(v, red, tid);
  if (tid == 0) out[b] = S / (float)L;
}

extern "C" void kernel_launch(void* const* d_in, const int* in_sizes, int n_in,
                              void* d_out, int out_size, void* d_ws, size_t ws_size,
                              hipStream_t stream) {
  const float* x        = (const float*)d_in[0];
  const int*   lengths  = (const int*)d_in[1];
  const float* h0_noise = (const float*)d_in[3];
  const float* W_lin_in = (const float*)d_in[4];
  const float* b_lin_in = (const float*)d_in[5];
  const float* g_ln1    = (const float*)d_in[6];
  const float* b_ln1    = (const float*)d_in[7];
  const float* W_ih     = (const float*)d_in[8];
  const float* W_hh     = (const float*)d_in[9];
  const float* b_ih     = (const float*)d_in[10];
  const float* b_hh     = (const float*)d_in[11];
  const float* W_init   = (const float*)d_in[12];
  const float* b_init   = (const float*)d_in[13];
  const float* W_lin1   = (const float*)d_in[14];
  const float* b_lin1   = (const float*)d_in[15];
  const float* g_ln2    = (const float*)d_in[16];
  const float* b_ln2    = (const float*)d_in[17];
  const float* W_mu     = (const float*)d_in[18];
  const float* b_mu     = (const float*)d_in[19];
  const float* W_sig    = (const float*)d_in[20];
  const float* b_sig    = (const float*)d_in[21];

  char* ws = (char*)d_ws;
  size_t off = 0;
  auto alloc = [&](size_t bytes) -> void* {
    void* p = ws + off;
    off += (bytes + 255) & ~(size_t)255;
    return p;
  };
  unsigned short* xbf      = (unsigned short*)alloc(16384ull * 768 * 2);
  unsigned short* Wlin_bf  = (unsigned short*)alloc(400ull * 768 * 2);
  unsigned short* Wih_bf   = (unsigned short*)alloc(1536ull * 448 * 2);
  unsigned short* Whh_bf   = (unsigned short*)alloc(1536ull * 512 * 2);
  unsigned short* Wlin1_bf = (unsigned short*)alloc(768ull * 512 * 2);
  unsigned short* Wmu_bf   = (unsigned short*)alloc(768ull * 768 * 2);
  unsigned short* Wsig_bf  = (unsigned short*)alloc(768ull * 768 * 2);
  float*          y        = (float*)alloc(16384ull * 768 * 4);   // y1 (ld448) then y2 (ld768)
  unsigned short* r_bf     = (unsigned short*)alloc(16384ull * 448 * 2);
  unsigned short* gi_bf    = (unsigned short*)alloc(16384ull * 1536 * 2);
  float*          h0f      = (float*)alloc(64ull * 512 * 4);
  unsigned short* hbf0     = (unsigned short*)alloc(64ull * 512 * 2);
  unsigned short* hbf1     = (unsigned short*)alloc(64ull * 512 * 2);
  unsigned short* hseq     = (unsigned short*)alloc(16384ull * 512 * 2);
  unsigned short* hh_bf    = (unsigned short*)alloc(16384ull * 768 * 2);
  unsigned short* mu_bf    = (unsigned short*)alloc(16384ull * 768 * 2);
  unsigned short* ls_bf    = (unsigned short*)alloc(16384ull * 768 * 2);
  float*          lp       = (float*)alloc(16384ull * 4);
  unsigned*       flags    = (unsigned*)alloc(1024);
  if (off > ws_size) return;  // workspace too small: leave output zeroed as a clear signal

  auto cgrid = [](long long n) { long long b = (n + 255) / 256; return (int)(b > 4096 ? 4096 : b); };

  // fp32 -> bf16 conversions (+ zero K-pad for W_ih)
  k_conv<<<dim3(cgrid(16384ll * 768)), 256, 0, stream>>>(x, xbf, 16384, 768, 768);
  k_conv<<<dim3(cgrid(400ll * 768)),   256, 0, stream>>>(W_lin_in, Wlin_bf, 400, 768, 768);
  k_conv<<<dim3(cgrid(1536ll * 448)),  256, 0, stream>>>(W_ih, Wih_bf, 1536, 400, 448);
  k_conv<<<dim3(cgrid(1536ll * 512)),  256, 0, stream>>>(W_hh, Whh_bf, 1536, 512, 512);
  k_conv<<<dim3(cgrid(768ll * 512)),   256, 0, stream>>>(W_lin1, Wlin1_bf, 768, 512, 512);
  k_conv<<<dim3(cgrid(768ll * 768)),   256, 0, stream>>>(W_mu, Wmu_bf, 768, 768, 768);
  k_conv<<<dim3(cgrid(768ll * 768)),   256, 0, stream>>>(W_sig, Wsig_bf, 768, 768, 768);

  // h0 (f32 + bf16)
  k_h0<<<dim3(64), 512, 0, stream>>>(h0_noise, W_init, b_init, h0f, hbf0);

  // y1 = x @ W_lin_in^T + b  (f32 out, ld 448, N=400)
  k_gemm<0><<<dim3(4, 128), 256, 0, stream>>>(xbf, 768, Wlin_bf, 768, 400,
                                              y, nullptr, 448, b_lin_in, 400, 768);
  // r = relu(LN(y1)) -> bf16 [16384][448], zero pad cols 400..447
  k_ln<<<dim3(16384), 256, 0, stream>>>(y, 448, 400, r_bf, 448, 448, g_ln1, b_ln1);
  // gi = r @ W_ih^T + b_ih (bf16 out)
  k_gemm<1><<<dim3(12, 128), 256, 0, stream>>>(r_bf, 448, Wih_bf, 448, 1536,
                                               nullptr, gi_bf, 1536, b_ih, 1536, 448);

  // GRU scan: persistent 32-block kernel, wave-mailbox barrier
  k_zero<<<dim3(1), 256, 0, stream>>>(flags);
  k_scan<<<dim3(32), 256, 0, stream>>>(gi_bf, Whh_bf, b_hh, h0f, hbf0, hbf1, hseq, flags);

  // y2 = hseq @ W_lin1^T + b (f32 out, ld 768)
  k_gemm<0><<<dim3(6, 128), 256, 0, stream>>>(hseq, 512, Wlin1_bf, 512, 768,
                                              y, nullptr, 768, b_lin1, 768, 512);
  // hh = relu(LN(y2)) -> bf16 [16384][768]
  k_ln<<<dim3(16384), 256, 0, stream>>>(y, 768, 768, hh_bf, 768, 768, g_ln2, b_ln2);
  // mu, logsig (bf16 out)
  k_gemm<1><<<dim3(6, 128), 256, 0, stream>>>(hh_bf, 768, Wmu_bf, 768, 768,
                                              nullptr, mu_bf, 768, b_mu, 768, 768);
  k_gemm<1><<<dim3(6, 128), 256, 0, stream>>>(hh_bf, 768, Wsig_bf, 768, 768,
                                              nullptr, ls_bf, 768, b_sig, 768, 768);

  // lp[b*256+t], then masked mean over t
  k_logprob<<<dim3(16384), 256, 0, stream>>>(x, mu_bf, ls_bf, lp);
  k_final<<<dim3(64), 256, 0, stream>>>(lp, lengths, (float*)d_out);
}